// Round 3
// baseline (44.717 us; speedup 1.0000x reference)
//
#include <hip/hip_runtime.h>
#include <math.h>

#define BB 32
#define MM 256
#define H2 32
#define NOUT 8

// sinh(t) up to sign (caller squares it). Series keeps relative accuracy for
// small t; exp formula for |t| >= 0.5.
__device__ __forceinline__ float sinh_mag(float t) {
    float a  = fabsf(t);
    float e  = __expf(a);
    float big = 0.5f * (e - __builtin_amdgcn_rcpf(e));
    float t2 = t * t;
    float small = t + t * t2 * (1.0f/6.0f + t2 * (1.0f/120.0f));
    return (a < 0.5f) ? small : big;
}

// sin(t) up to sign (caller squares it). Series for small t avoids the
// cos-cancellation region; hw sin elsewhere.
__device__ __forceinline__ float sin_mag(float t) {
    float a  = fabsf(t);
    float t2 = t * t;
    float small = t + t * t2 * (-1.0f/6.0f + t2 * (1.0f/120.0f));
    float big = __sinf(t);
    return (a < 0.5f) ? small : big;
}

__global__ __launch_bounds__(256) void interaction_kernel(
    const float* __restrict__ x, const int* __restrict__ mask,
    const float* __restrict__ W1, const float* __restrict__ b1,
    const float* __restrict__ W2, const float* __restrict__ b2,
    float* __restrict__ out)
{
    // block covers 4 consecutive i-rows of one batch; one wave per i-row
    const int blk = blockIdx.x;          // 0 .. B*M/4 - 1
    const int b   = blk >> 6;            // 64 blocks per batch
    const int i0  = (blk & 63) << 2;
    const int wid = threadIdx.x >> 6;    // wave id 0..3
    const int l   = threadIdx.x & 63;    // lane
    const int i   = i0 + wid;
    const int j0  = l << 2;              // 4 consecutive j per lane

    float4* outv = (float4*)(out + ((size_t)(b * NOUT)) * (MM * MM)
                                 + (size_t)i * MM + j0);
    const int PSTRIDE4 = MM * MM / 4;    // float4 plane stride

    const int mi = mask[b * MM + i];
    if (mi == 0) {                        // wave-uniform branch
        float4 z4 = make_float4(0.f, 0.f, 0.f, 0.f);
        #pragma unroll
        for (int p = 0; p < NOUT; ++p) outv[p * PSTRIDE4] = z4;
        return;
    }

    // i-side (wave-uniform)
    const float eta_i = x[(b * MM + i) * 3 + 0];
    const float phi_i = x[(b * MM + i) * 3 + 1];
    const float lpt_i = x[(b * MM + i) * 3 + 2];

    // j-side: 12 contiguous floats per lane = 3x float4
    const float4* xr = (const float4*)(x + (size_t)(b * MM) * 3);
    const float4 xa = xr[l * 3 + 0];
    const float4 xb = xr[l * 3 + 1];
    const float4 xc = xr[l * 3 + 2];
    const int4 mj4 = *(const int4*)(mask + b * MM + j0);

    const float eta_j[4] = { xa.x, xa.w, xb.z, xc.y };
    const float phi_j[4] = { xa.y, xb.x, xb.w, xc.z };
    const float lpt_j[4] = { xa.z, xb.y, xc.x, xc.w };
    const float mf[4] = { mj4.x ? 1.f : 0.f, mj4.y ? 1.f : 0.f,
                          mj4.z ? 1.f : 0.f, mj4.w ? 1.f : 0.f };

    // features per j
    float fmass[4], fdr[4], fkt[4];
    #pragma unroll
    for (int jj = 0; jj < 4; ++jj) {
        const float dx  = eta_i - eta_j[jj];
        const float dy  = phi_i - phi_j[jj];
        const float dr2 = dx * dx + dy * dy;

        const float L = (dr2 > 0.f) ? 0.5f * __logf(dr2) : 0.f;
        fdr[jj] = L;
        fkt[jj] = (dr2 > 0.f) ? fminf(lpt_i, lpt_j[jj]) + L : 0.f;

        // cosh(dx) - cos(dy) = 2*(sinh^2(dx/2) + sin^2(dy/2))  (cancellation-free)
        const float sh = sinh_mag(0.5f * dx);
        const float sn = sin_mag(0.5f * dy);
        const float c  = 2.0f * (sh * sh + sn * sn);
        fmass[jj] = (c > 0.f) ? __logf(2.0f * c) + lpt_i + lpt_j[jj] : 0.f;
    }

    // MLP: feat[3] -> leaky_relu(H2) -> NOUT, 4 pairs at once
    float o[4][NOUT];
    #pragma unroll
    for (int jj = 0; jj < 4; ++jj)
        #pragma unroll
        for (int p = 0; p < NOUT; ++p) o[jj][p] = b2[p];

    #pragma unroll
    for (int k = 0; k < H2; ++k) {
        const float w0 = W1[k * 3 + 0];
        const float w1 = W1[k * 3 + 1];
        const float w2 = W1[k * 3 + 2];
        const float bk = b1[k];
        float z[4];
        #pragma unroll
        for (int jj = 0; jj < 4; ++jj) {
            float t = bk;
            t = fmaf(fmass[jj], w0, t);
            t = fmaf(fdr[jj],   w1, t);
            t = fmaf(fkt[jj],   w2, t);
            z[jj] = (t >= 0.f) ? t : 0.01f * t;
        }
        #pragma unroll
        for (int p = 0; p < NOUT; ++p) {
            const float wv = W2[p * H2 + k];
            #pragma unroll
            for (int jj = 0; jj < 4; ++jj)
                o[jj][p] = fmaf(z[jj], wv, o[jj][p]);
        }
    }

    #pragma unroll
    for (int p = 0; p < NOUT; ++p) {
        float4 v = make_float4(o[0][p] * mf[0], o[1][p] * mf[1],
                               o[2][p] * mf[2], o[3][p] * mf[3]);
        outv[p * PSTRIDE4] = v;
    }
}

extern "C" void kernel_launch(void* const* d_in, const int* in_sizes, int n_in,
                              void* d_out, int out_size, void* d_ws, size_t ws_size,
                              hipStream_t stream) {
    const float* x    = (const float*)d_in[0];
    const int*   mask = (const int*)d_in[1];
    const float* W1   = (const float*)d_in[2];
    const float* b1   = (const float*)d_in[3];
    const float* W2   = (const float*)d_in[4];
    const float* b2   = (const float*)d_in[5];
    float* out = (float*)d_out;

    dim3 grid(BB * MM / 4);
    dim3 block(256);
    interaction_kernel<<<grid, block, 0, stream>>>(x, mask, W1, b1, W2, b2, out);
}

// Round 4
// 24.529 us; speedup vs baseline: 1.8230x; 1.8230x over previous
//
#include <hip/hip_runtime.h>
#include <math.h>

#define BB 32
#define MM 256
#define H2 32
#define NOUT 8

// sinh(t) up to sign (caller squares it). Series keeps relative accuracy for
// small t; exp formula for |t| >= 0.5.
__device__ __forceinline__ float sinh_mag(float t) {
    float a  = fabsf(t);
    float e  = __expf(a);
    float big = 0.5f * (e - __builtin_amdgcn_rcpf(e));
    float t2 = t * t;
    float small = t + t * t2 * (1.0f/6.0f + t2 * (1.0f/120.0f));
    return (a < 0.5f) ? small : big;
}

// sin(t) up to sign (caller squares it). Series for small t avoids the
// cos-cancellation region; hw sin elsewhere.
__device__ __forceinline__ float sin_mag(float t) {
    float a  = fabsf(t);
    float t2 = t * t;
    float small = t + t * t2 * (-1.0f/6.0f + t2 * (1.0f/120.0f));
    float big = __sinf(t);
    return (a < 0.5f) ? small : big;
}

__global__ __launch_bounds__(256) void interaction_kernel(
    const float* __restrict__ x, const int* __restrict__ mask,
    const float* __restrict__ W1, const float* __restrict__ b1,
    const float* __restrict__ W2, const float* __restrict__ b2,
    float* __restrict__ out)
{
    // XCD-chunked swizzle: 8192 blocks, 8 XCDs -> each XCD gets a contiguous
    // 1024-block chunk (contiguous (b,i) range -> contiguous write region).
    const int bid = blockIdx.x;
    const int nb  = (bid & 7) * 1024 + (bid >> 3);
    const int b   = nb >> 8;
    const int i   = nb & 255;
    const int j   = threadIdx.x;

    float* op = out + ((size_t)(b * NOUT)) * (MM * MM) + (size_t)i * MM + j;
    const int PSTRIDE = MM * MM;

    const int mi = mask[b * MM + i];   // block-uniform
    if (mi == 0) {
        #pragma unroll
        for (int p = 0; p < NOUT; ++p)
            __builtin_nontemporal_store(0.f, op + p * PSTRIDE);
        return;
    }

    // i-side (block-uniform -> scalar loads)
    const float eta_i = x[(b * MM + i) * 3 + 0];
    const float phi_i = x[(b * MM + i) * 3 + 1];
    const float lpt_i = x[(b * MM + i) * 3 + 2];

    // j-side per-thread
    const float eta_j = x[(b * MM + j) * 3 + 0];
    const float phi_j = x[(b * MM + j) * 3 + 1];
    const float lpt_j = x[(b * MM + j) * 3 + 2];
    const float mf    = mask[b * MM + j] ? 1.f : 0.f;

    const float dx  = eta_i - eta_j;
    const float dy  = phi_i - phi_j;
    const float dr2 = dx * dx + dy * dy;

    const float L      = (dr2 > 0.f) ? 0.5f * __logf(dr2) : 0.f;
    const float fdr    = L;
    const float fkt    = (dr2 > 0.f) ? fminf(lpt_i, lpt_j) + L : 0.f;

    // cosh(dx) - cos(dy) = 2*(sinh^2(dx/2) + sin^2(dy/2))  (cancellation-free)
    const float sh = sinh_mag(0.5f * dx);
    const float sn = sin_mag(0.5f * dy);
    const float c  = 2.0f * (sh * sh + sn * sn);
    const float fmass = (c > 0.f) ? __logf(2.0f * c) + lpt_i + lpt_j : 0.f;

    float o[NOUT];
    #pragma unroll
    for (int p = 0; p < NOUT; ++p) o[p] = b2[p];

    #pragma unroll
    for (int k = 0; k < H2; ++k) {
        float z = b1[k];
        z = fmaf(fmass, W1[k * 3 + 0], z);
        z = fmaf(fdr,   W1[k * 3 + 1], z);
        z = fmaf(fkt,   W1[k * 3 + 2], z);
        z = (z >= 0.f) ? z : 0.01f * z;   // leaky_relu
        #pragma unroll
        for (int p = 0; p < NOUT; ++p)
            o[p] = fmaf(z, W2[p * H2 + k], o[p]);
    }

    #pragma unroll
    for (int p = 0; p < NOUT; ++p)
        __builtin_nontemporal_store(o[p] * mf, op + p * PSTRIDE);
}

extern "C" void kernel_launch(void* const* d_in, const int* in_sizes, int n_in,
                              void* d_out, int out_size, void* d_ws, size_t ws_size,
                              hipStream_t stream) {
    const float* x    = (const float*)d_in[0];
    const int*   mask = (const int*)d_in[1];
    const float* W1   = (const float*)d_in[2];
    const float* b1   = (const float*)d_in[3];
    const float* W2   = (const float*)d_in[4];
    const float* b2   = (const float*)d_in[5];
    float* out = (float*)d_out;

    dim3 grid(BB * MM);
    dim3 block(MM);
    interaction_kernel<<<grid, block, 0, stream>>>(x, mask, W1, b1, W2, b2, out);
}